// Round 2
// baseline (454.275 us; speedup 1.0000x reference)
//
#include <hip/hip_runtime.h>

// IDWT (Haar, stride-2 transposed conv, grouped):
//   x: [B, 4C, H, W] f32, filters: [4,2,2] f32
//   out[b, c, 2h+p, 2w+q] = sum_s x[b, s*C+c, h, w] * f[s, p, q]
// B=16, 4C=256 (C=64), H=W=128 -> out [16, 64, 256, 256]
//
// Pure streaming kernel: 268 MB in + 268 MB out, each byte touched once.
// Nontemporal (nt) loads/stores keep the streams from thrashing L2.

constexpr int B = 16;
constexpr int C = 64;
constexpr int H = 128;
constexpr int W = 128;
constexpr int W4 = W / 4;                 // 32 quads per row
constexpr long N_THREADS = (long)B * C * H * W4;   // 4,194,304

typedef float f32x4 __attribute__((ext_vector_type(4)));

__global__ __launch_bounds__(256) void idwt_kernel(
    const float* __restrict__ x,
    const float* __restrict__ f,
    float* __restrict__ out)
{
    const int idx = blockIdx.x * 256 + threadIdx.x;

    // idx -> (b, c, h, w4); all dims are powers of two
    const int w4 = idx & (W4 - 1);        // 5 bits
    const int h  = (idx >> 5) & (H - 1);  // 7 bits
    const int c  = (idx >> 12) & (C - 1); // 6 bits
    const int b  = idx >> 18;

    const long sStride = (long)C * H * W;                       // subband stride
    const long inBase  = (((long)b * 4 * C + c) * H + h) * W + (long)w4 * 4;

    const f32x4 va = __builtin_nontemporal_load((const f32x4*)(x + inBase));
    const f32x4 vb = __builtin_nontemporal_load((const f32x4*)(x + inBase + sStride));
    const f32x4 vc = __builtin_nontemporal_load((const f32x4*)(x + inBase + 2 * sStride));
    const f32x4 vd = __builtin_nontemporal_load((const f32x4*)(x + inBase + 3 * sStride));

    // filters[s][p][q], flat: f[s*4 + p*2 + q] -- uniform addresses -> s_load
    const float f00 = f[0],  f01 = f[1],  f02 = f[2],  f03 = f[3];
    const float f10 = f[4],  f11 = f[5],  f12 = f[6],  f13 = f[7];
    const float f20 = f[8],  f21 = f[9],  f22 = f[10], f23 = f[11];
    const float f30 = f[12], f31 = f[13], f32 = f[14], f33 = f[15];

    f32x4 r0a, r0b, r1a, r1b;
    #pragma unroll
    for (int j = 0; j < 4; ++j) {
        const float a = va[j], bb = vb[j], cc = vc[j], dd = vd[j];
        const float e00 = a*f00 + bb*f10 + cc*f20 + dd*f30;   // p=0,q=0
        const float e01 = a*f01 + bb*f11 + cc*f21 + dd*f31;   // p=0,q=1
        const float e10 = a*f02 + bb*f12 + cc*f22 + dd*f32;   // p=1,q=0
        const float e11 = a*f03 + bb*f13 + cc*f23 + dd*f33;   // p=1,q=1
        if (j < 2) {
            r0a[2*j] = e00; r0a[2*j+1] = e01;
            r1a[2*j] = e10; r1a[2*j+1] = e11;
        } else {
            r0b[2*(j-2)] = e00; r0b[2*(j-2)+1] = e01;
            r1b[2*(j-2)] = e10; r1b[2*(j-2)+1] = e11;
        }
    }

    // output: rows 2h and 2h+1, cols 8*w4 .. 8*w4+7 (contiguous)
    const long outBase = (((long)b * C + c) * (2 * H) + (long)2 * h) * (2 * W)
                         + (long)w4 * 8;
    __builtin_nontemporal_store(r0a, (f32x4*)(out + outBase));
    __builtin_nontemporal_store(r0b, (f32x4*)(out + outBase + 4));
    __builtin_nontemporal_store(r1a, (f32x4*)(out + outBase + 2 * W));
    __builtin_nontemporal_store(r1b, (f32x4*)(out + outBase + 2 * W + 4));
}

extern "C" void kernel_launch(void* const* d_in, const int* in_sizes, int n_in,
                              void* d_out, int out_size, void* d_ws, size_t ws_size,
                              hipStream_t stream) {
    const float* x = (const float*)d_in[0];
    const float* f = (const float*)d_in[1];
    float* out = (float*)d_out;

    const int threads = 256;
    const int blocks = (int)(N_THREADS / threads);  // 16384, exact
    idwt_kernel<<<blocks, threads, 0, stream>>>(x, f, out);
}